// Round 5
// baseline (74.734 us; speedup 1.0000x reference)
//
#include <hip/hip_runtime.h>

// Shapes (compile-time constants from the reference)
#define BQ 4     // B
#define VV 384   // V visible nodes
#define HH 128   // H hidden nodes
#define NN 512   // N = V + H
#define HDIM 64  // HD
#define TD 128   // T*D

// ws layout (floats): E2 (B*N*64 = 131072 floats), then barrier counter
#define OFF_E2   0
#define OFF_BAR  (BQ * NN * HDIM)   // 1 unsigned at this float offset

// Device-scope grid barrier. Requires all blocks co-resident:
// 512 blocks x 512 thr, 2KB LDS, low VGPR -> 2 blocks/CU on 256 CUs. OK.
__device__ __forceinline__ void grid_barrier(unsigned* cnt, unsigned nblk) {
    __syncthreads();
    if (threadIdx.x == 0) {
        __threadfence();                       // release E2 writes device-wide
        atomicAdd(cnt, 1u);                    // device scope by default
        while (__hip_atomic_load(cnt, __ATOMIC_RELAXED, __HIP_MEMORY_SCOPE_AGENT) < nblk)
            __builtin_amdgcn_s_sleep(2);
        __threadfence();                       // acquire
    }
    __syncthreads();
}

// Fused: phase 1 = R2 k_rowpipe (waves 0-3, 4 rows/block);
//        phase 2 = R2 k_agg_out (whole block, row = blockIdx.x).
__global__ __launch_bounds__(512) void k_fused(
    const float* __restrict__ x,       // (B,V,128)
    const float* __restrict__ adj,     // (B,N,N)
    const float* __restrict__ w_in1, const float* __restrict__ b_in1,
    const float* __restrict__ w_in2, const float* __restrict__ b_in2,
    const float* __restrict__ w_e1,  const float* __restrict__ b_e1,
    const float* __restrict__ w_e2,  const float* __restrict__ b_e2,
    const float* __restrict__ w_n1,  const float* __restrict__ b_n1,
    const float* __restrict__ w_n2,  const float* __restrict__ b_n2,
    const float* __restrict__ w_out, const float* __restrict__ b_out,
    float* __restrict__ E2, unsigned* __restrict__ bar,
    float* __restrict__ out)           // (B,H,128)
{
    const int wid  = threadIdx.x >> 6;    // 0..7
    const int lane = threadIdx.x & 63;

    // ---------------- phase 1: E2 rows (waves 0-3) ----------------
    if (wid < 4) {
        const int row = blockIdx.x * 4 + wid;   // 0 .. 2047
        const int b = row / NN;
        const int j = row % NN;

        float bbv = 0.f;
        if (j < VV) {  // wave-uniform branch
            const float* xr = x + (size_t)(b * VV + j) * TD;
            const float xv0 = xr[lane];
            const float xv1 = xr[64 + lane];

            float a0 = b_in1[lane], a1 = 0.f;
            #pragma unroll 8
            for (int k = 0; k < HDIM; ++k) {
                a0 = fmaf(__shfl(xv0, k, 64), w_in1[k * HDIM + lane], a0);
                a1 = fmaf(__shfl(xv1, k, 64), w_in1[(HDIM + k) * HDIM + lane], a1);
            }
            const float h1 = fmaxf(a0 + a1, 0.f);

            a0 = b_in2[lane]; a1 = 0.f;
            #pragma unroll 8
            for (int k = 0; k < HDIM; k += 2) {
                a0 = fmaf(__shfl(h1, k, 64),     w_in2[k * HDIM + lane],       a0);
                a1 = fmaf(__shfl(h1, k + 1, 64), w_in2[(k + 1) * HDIM + lane], a1);
            }
            const float h2 = fmaxf(a0 + a1, 0.f);

            a0 = 0.f; a1 = 0.f;
            #pragma unroll 8
            for (int k = 0; k < HDIM; k += 2) {
                a0 = fmaf(__shfl(h2, k, 64),     w_e1[(HDIM + k) * HDIM + lane],     a0);
                a1 = fmaf(__shfl(h2, k + 1, 64), w_e1[(HDIM + k + 1) * HDIM + lane], a1);
            }
            bbv = a0 + a1;
        }

        const float e1 = fmaxf(bbv + b_e1[lane], 0.f);
        float a0 = b_e2[lane], a1 = 0.f;
        #pragma unroll 8
        for (int k = 0; k < HDIM; k += 2) {
            a0 = fmaf(__shfl(e1, k, 64),     w_e2[k * HDIM + lane],       a0);
            a1 = fmaf(__shfl(e1, k + 1, 64), w_e2[(k + 1) * HDIM + lane], a1);
        }
        E2[(size_t)row * HDIM + lane] = fmaxf(a0 + a1, 0.f);
    }

    // ---------------- grid barrier ----------------
    grid_barrier(bar, gridDim.x);

    // ---------------- phase 2: one output row per block ----------------
    const int row = blockIdx.x;          // 0 .. B*H-1
    const int b   = row / HH;
    const int hi  = row % HH;
    const int i   = VV + hi;

    const float* adjrow = adj + ((size_t)b * NN + i) * NN;
    const float* e2b    = E2 + ((size_t)b * NN + wid * 64) * HDIM;

    const float adjv = adjrow[wid * 64 + lane];

    float c0 = 0.f, c1 = 0.f, c2 = 0.f, c3 = 0.f;
    #pragma unroll 8
    for (int jj = 0; jj < 64; jj += 4) {
        c0 = fmaf(__shfl(adjv, jj,     64), e2b[(jj)     * HDIM + lane], c0);
        c1 = fmaf(__shfl(adjv, jj + 1, 64), e2b[(jj + 1) * HDIM + lane], c1);
        c2 = fmaf(__shfl(adjv, jj + 2, 64), e2b[(jj + 2) * HDIM + lane], c2);
        c3 = fmaf(__shfl(adjv, jj + 3, 64), e2b[(jj + 3) * HDIM + lane], c3);
    }

    __shared__ float red[8][HDIM];
    red[wid][lane] = (c0 + c1) + (c2 + c3);
    __syncthreads();
    if (wid != 0) return;

    const float acc = ((red[0][lane] + red[1][lane]) + (red[2][lane] + red[3][lane]))
                    + ((red[4][lane] + red[5][lane]) + (red[6][lane] + red[7][lane]));

    float t0 = b_n1[lane], t1 = 0.f;
    #pragma unroll 8
    for (int k = 0; k < HDIM; k += 2) {
        t0 = fmaf(__shfl(acc, k, 64),     w_n1[k * HDIM + lane],       t0);
        t1 = fmaf(__shfl(acc, k + 1, 64), w_n1[(k + 1) * HDIM + lane], t1);
    }
    const float n1 = fmaxf(t0 + t1, 0.f);

    t0 = b_n2[lane]; t1 = 0.f;
    #pragma unroll 8
    for (int k = 0; k < HDIM; k += 2) {
        t0 = fmaf(__shfl(n1, k, 64),     w_n2[k * HDIM + lane],       t0);
        t1 = fmaf(__shfl(n1, k + 1, 64), w_n2[(k + 1) * HDIM + lane], t1);
    }
    const float n2 = fmaxf(t0 + t1, 0.f);

    float o0 = b_out[lane], o0b = 0.f;
    float o1 = b_out[64 + lane], o1b = 0.f;
    #pragma unroll 8
    for (int k = 0; k < HDIM; k += 2) {
        const float v0 = __shfl(n2, k, 64);
        const float v1 = __shfl(n2, k + 1, 64);
        o0  = fmaf(v0, w_out[k * TD + lane],            o0);
        o0b = fmaf(v1, w_out[(k + 1) * TD + lane],      o0b);
        o1  = fmaf(v0, w_out[k * TD + 64 + lane],       o1);
        o1b = fmaf(v1, w_out[(k + 1) * TD + 64 + lane], o1b);
    }
    float* orow = out + (size_t)row * TD;
    orow[lane]      = o0 + o0b;
    orow[64 + lane] = o1 + o1b;
}

extern "C" void kernel_launch(void* const* d_in, const int* in_sizes, int n_in,
                              void* d_out, int out_size, void* d_ws, size_t ws_size,
                              hipStream_t stream) {
    const float* x     = (const float*)d_in[0];
    const float* adj   = (const float*)d_in[1];
    const float* w_in1 = (const float*)d_in[2];
    const float* b_in1 = (const float*)d_in[3];
    const float* w_in2 = (const float*)d_in[4];
    const float* b_in2 = (const float*)d_in[5];
    const float* w_e1  = (const float*)d_in[6];
    const float* b_e1  = (const float*)d_in[7];
    const float* w_e2  = (const float*)d_in[8];
    const float* b_e2  = (const float*)d_in[9];
    const float* w_n1  = (const float*)d_in[10];
    const float* b_n1  = (const float*)d_in[11];
    const float* w_n2  = (const float*)d_in[12];
    const float* b_n2  = (const float*)d_in[13];
    const float* w_out = (const float*)d_in[14];
    const float* b_out = (const float*)d_in[15];
    float* out = (float*)d_out;
    float* ws  = (float*)d_ws;
    float* E2  = ws + OFF_E2;
    unsigned* bar = (unsigned*)(ws + OFF_BAR);

    // reset barrier counter (poison-safe, graph-capture-safe, deterministic)
    hipMemsetAsync(bar, 0, sizeof(unsigned), stream);

    k_fused<<<BQ * HH, 512, 0, stream>>>(
        x, adj, w_in1, b_in1, w_in2, b_in2, w_e1, b_e1, w_e2, b_e2,
        w_n1, b_n1, w_n2, b_n2, w_out, b_out, E2, bar, out);
}

// Round 6
// 24.150 us; speedup vs baseline: 3.0946x; 3.0946x over previous
//
#include <hip/hip_runtime.h>

// Shapes (compile-time constants from the reference)
#define BQ 4     // B
#define VV 384   // V visible nodes
#define HH 128   // H hidden nodes
#define NN 512   // N = V + H
#define HDIM 64  // HD
#define TD 128   // T*D

// K1: per-row pipeline. One wave (64 lanes) per (b, j) row, j in [0, N).
// Grid is exactly B*N/4 blocks of 256 (4 waves) -> no bounds guard needed.
// The three 64x64 weight mats used by every row are staged in LDS (48 KB,
// 2 blocks/CU still fit); w_in1 (32 KB) stays in global and exactly fits L1.
__global__ __launch_bounds__(256) void k_rowpipe(
    const float* __restrict__ x,       // (B,V,128)
    const float* __restrict__ w_in1,   // (128,64)
    const float* __restrict__ b_in1,   // (64)
    const float* __restrict__ w_in2,   // (64,64)
    const float* __restrict__ b_in2,   // (64)
    const float* __restrict__ w_e1,    // (128,64) ; rows [64:128) = sender half
    const float* __restrict__ b_e1,    // (64)
    const float* __restrict__ w_e2,    // (64,64)
    const float* __restrict__ b_e2,    // (64)
    float* __restrict__ E2)            // (B,N,64) in workspace
{
    __shared__ float sw2[HDIM * HDIM];   // w_in2
    __shared__ float se1[HDIM * HDIM];   // w_e1 sender half
    __shared__ float se2[HDIM * HDIM];   // w_e2

    {   // float4 staging: 1024 float4 per matrix, 4 per thread
        const float4* s2 = (const float4*)w_in2;
        const float4* s3 = (const float4*)(w_e1 + HDIM * HDIM);
        const float4* s4 = (const float4*)w_e2;
        float4* d2 = (float4*)sw2;
        float4* d3 = (float4*)se1;
        float4* d4 = (float4*)se2;
        #pragma unroll
        for (int t = 0; t < 4; ++t) {
            const int idx = threadIdx.x + t * 256;
            d2[idx] = s2[idx];
            d3[idx] = s3[idx];
            d4[idx] = s4[idx];
        }
    }
    __syncthreads();

    const int wave = (blockIdx.x * blockDim.x + threadIdx.x) >> 6;
    const int lane = threadIdx.x & 63;
    const int b = wave / NN;
    const int j = wave % NN;

    float bbv = 0.f;
    if (j < VV) {  // wave-uniform branch (one row per wave)
        const float* xr = x + (size_t)(b * VV + j) * TD;
        // coalesced load of the x row, then shfl-broadcast (no uniform loads)
        const float xv0 = xr[lane];
        const float xv1 = xr[64 + lane];

        float a0 = b_in1[lane], a1 = 0.f;
        #pragma unroll 8
        for (int k = 0; k < HDIM; ++k) {
            a0 = fmaf(__shfl(xv0, k, 64), w_in1[k * HDIM + lane], a0);
            a1 = fmaf(__shfl(xv1, k, 64), w_in1[(HDIM + k) * HDIM + lane], a1);
        }
        const float h1 = fmaxf(a0 + a1, 0.f);

        a0 = b_in2[lane]; a1 = 0.f;
        #pragma unroll 8
        for (int k = 0; k < HDIM; k += 2) {
            a0 = fmaf(__shfl(h1, k, 64),     sw2[k * HDIM + lane],       a0);
            a1 = fmaf(__shfl(h1, k + 1, 64), sw2[(k + 1) * HDIM + lane], a1);
        }
        const float h2 = fmaxf(a0 + a1, 0.f);

        a0 = 0.f; a1 = 0.f;
        #pragma unroll 8
        for (int k = 0; k < HDIM; k += 2) {
            a0 = fmaf(__shfl(h2, k, 64),     se1[k * HDIM + lane],       a0);
            a1 = fmaf(__shfl(h2, k + 1, 64), se1[(k + 1) * HDIM + lane], a1);
        }
        bbv = a0 + a1;
    }

    const float e1 = fmaxf(bbv + b_e1[lane], 0.f);
    float a0 = b_e2[lane], a1 = 0.f;
    #pragma unroll 8
    for (int k = 0; k < HDIM; k += 2) {
        a0 = fmaf(__shfl(e1, k, 64),     se2[k * HDIM + lane],       a0);
        a1 = fmaf(__shfl(e1, k + 1, 64), se2[(k + 1) * HDIM + lane], a1);
    }
    E2[(size_t)wave * HDIM + lane] = fmaxf(a0 + a1, 0.f);
}

// K2: one block (8 waves, 512 threads) per hidden receiver row (b, i=V+hi).
// wave w sums j in [64w, 64w+64); LDS-reduce; wave 0 does node MLP + out.
__global__ __launch_bounds__(512) void k_agg_out(
    const float* __restrict__ adj,   // (B,N,N)
    const float* __restrict__ E2,    // (B,N,64)
    const float* __restrict__ w_n1, const float* __restrict__ b_n1,
    const float* __restrict__ w_n2, const float* __restrict__ b_n2,
    const float* __restrict__ w_out, // (64,128)
    const float* __restrict__ b_out, // (128)
    float* __restrict__ out)         // (B,H,128)
{
    const int row  = blockIdx.x;          // 0 .. B*H-1
    const int b    = row / HH;
    const int hi   = row % HH;
    const int i    = VV + hi;
    const int wid  = threadIdx.x >> 6;    // 0..7
    const int lane = threadIdx.x & 63;

    const float* adjrow = adj + ((size_t)b * NN + i) * NN;
    const float* e2b    = E2 + ((size_t)b * NN + wid * 64) * HDIM;

    // coalesced load of this wave's 64 adj weights, then broadcast
    const float adjv = adjrow[wid * 64 + lane];

    float c0 = 0.f, c1 = 0.f, c2 = 0.f, c3 = 0.f;
    #pragma unroll
    for (int jj = 0; jj < 64; jj += 4) {
        c0 = fmaf(__shfl(adjv, jj,     64), e2b[(jj)     * HDIM + lane], c0);
        c1 = fmaf(__shfl(adjv, jj + 1, 64), e2b[(jj + 1) * HDIM + lane], c1);
        c2 = fmaf(__shfl(adjv, jj + 2, 64), e2b[(jj + 2) * HDIM + lane], c2);
        c3 = fmaf(__shfl(adjv, jj + 3, 64), e2b[(jj + 3) * HDIM + lane], c3);
    }
    const float acc_p = (c0 + c1) + (c2 + c3);

    __shared__ float red[8][HDIM];
    red[wid][lane] = acc_p;
    __syncthreads();
    if (wid != 0) return;

    const float acc = ((red[0][lane] + red[1][lane]) + (red[2][lane] + red[3][lane]))
                    + ((red[4][lane] + red[5][lane]) + (red[6][lane] + red[7][lane]));

    float t0 = b_n1[lane], t1 = 0.f;
    #pragma unroll 8
    for (int k = 0; k < HDIM; k += 2) {
        t0 = fmaf(__shfl(acc, k, 64),     w_n1[k * HDIM + lane],       t0);
        t1 = fmaf(__shfl(acc, k + 1, 64), w_n1[(k + 1) * HDIM + lane], t1);
    }
    const float n1 = fmaxf(t0 + t1, 0.f);

    t0 = b_n2[lane]; t1 = 0.f;
    #pragma unroll 8
    for (int k = 0; k < HDIM; k += 2) {
        t0 = fmaf(__shfl(n1, k, 64),     w_n2[k * HDIM + lane],       t0);
        t1 = fmaf(__shfl(n1, k + 1, 64), w_n2[(k + 1) * HDIM + lane], t1);
    }
    const float n2 = fmaxf(t0 + t1, 0.f);

    float o0 = b_out[lane], o0b = 0.f;
    float o1 = b_out[64 + lane], o1b = 0.f;
    #pragma unroll 8
    for (int k = 0; k < HDIM; k += 2) {
        const float v0 = __shfl(n2, k, 64);
        const float v1 = __shfl(n2, k + 1, 64);
        o0  = fmaf(v0, w_out[k * TD + lane],            o0);
        o0b = fmaf(v1, w_out[(k + 1) * TD + lane],      o0b);
        o1  = fmaf(v0, w_out[k * TD + 64 + lane],       o1);
        o1b = fmaf(v1, w_out[(k + 1) * TD + 64 + lane], o1b);
    }
    float* orow = out + (size_t)row * TD;
    orow[lane]      = o0 + o0b;
    orow[64 + lane] = o1 + o1b;
}

extern "C" void kernel_launch(void* const* d_in, const int* in_sizes, int n_in,
                              void* d_out, int out_size, void* d_ws, size_t ws_size,
                              hipStream_t stream) {
    const float* x     = (const float*)d_in[0];
    const float* adj   = (const float*)d_in[1];
    const float* w_in1 = (const float*)d_in[2];
    const float* b_in1 = (const float*)d_in[3];
    const float* w_in2 = (const float*)d_in[4];
    const float* b_in2 = (const float*)d_in[5];
    const float* w_e1  = (const float*)d_in[6];
    const float* b_e1  = (const float*)d_in[7];
    const float* w_e2  = (const float*)d_in[8];
    const float* b_e2  = (const float*)d_in[9];
    const float* w_n1  = (const float*)d_in[10];
    const float* b_n1  = (const float*)d_in[11];
    const float* w_n2  = (const float*)d_in[12];
    const float* b_n2  = (const float*)d_in[13];
    const float* w_out = (const float*)d_in[14];
    const float* b_out = (const float*)d_in[15];
    float* out = (float*)d_out;
    float* E2  = (float*)d_ws;   // B*N*64 floats = 512 KiB

    // K1: B*N = 2048 waves -> 512 blocks of 256 threads
    k_rowpipe<<<(BQ * NN * 64) / 256, 256, 0, stream>>>(
        x, w_in1, b_in1, w_in2, b_in2, w_e1, b_e1, w_e2, b_e2, E2);
    // K2: one 512-thread block per hidden row -> B*H = 512 blocks
    k_agg_out<<<BQ * HH, 512, 0, stream>>>(
        adj, E2, w_n1, b_n1, w_n2, b_n2, w_out, b_out, out);
}

// Round 7
// 22.005 us; speedup vs baseline: 3.3962x; 1.0975x over previous
//
#include <hip/hip_runtime.h>

// Shapes (compile-time constants from the reference)
#define BQ 4     // B
#define VV 384   // V visible nodes
#define HH 128   // H hidden nodes
#define NN 512   // N = V + H
#define HDIM 64  // HD
#define TD 128   // T*D

// K1: per-row pipeline (R2 form — proven best). One wave per (b, j) row.
__global__ __launch_bounds__(256) void k_rowpipe(
    const float* __restrict__ x,       // (B,V,128)
    const float* __restrict__ w_in1,   // (128,64)
    const float* __restrict__ b_in1,   // (64)
    const float* __restrict__ w_in2,   // (64,64)
    const float* __restrict__ b_in2,   // (64)
    const float* __restrict__ w_e1,    // (128,64) ; rows [64:128) = sender half
    const float* __restrict__ b_e1,    // (64)
    const float* __restrict__ w_e2,    // (64,64)
    const float* __restrict__ b_e2,    // (64)
    float* __restrict__ E2)            // (B,N,64) in workspace
{
    const int wave = (blockIdx.x * blockDim.x + threadIdx.x) >> 6;
    const int lane = threadIdx.x & 63;
    if (wave >= BQ * NN) return;
    const int b = wave / NN;
    const int j = wave % NN;

    float bbv = 0.f;
    if (j < VV) {  // wave-uniform branch (one row per wave)
        const float* xr = x + (size_t)(b * VV + j) * TD;
        const float xv0 = xr[lane];
        const float xv1 = xr[64 + lane];

        float a0 = b_in1[lane], a1 = 0.f;
        #pragma unroll 8
        for (int k = 0; k < HDIM; ++k) {
            a0 = fmaf(__shfl(xv0, k, 64), w_in1[k * HDIM + lane], a0);
            a1 = fmaf(__shfl(xv1, k, 64), w_in1[(HDIM + k) * HDIM + lane], a1);
        }
        const float h1 = fmaxf(a0 + a1, 0.f);

        a0 = b_in2[lane]; a1 = 0.f;
        #pragma unroll 8
        for (int k = 0; k < HDIM; k += 2) {
            a0 = fmaf(__shfl(h1, k, 64),     w_in2[k * HDIM + lane],       a0);
            a1 = fmaf(__shfl(h1, k + 1, 64), w_in2[(k + 1) * HDIM + lane], a1);
        }
        const float h2 = fmaxf(a0 + a1, 0.f);

        a0 = 0.f; a1 = 0.f;
        #pragma unroll 8
        for (int k = 0; k < HDIM; k += 2) {
            a0 = fmaf(__shfl(h2, k, 64),     w_e1[(HDIM + k) * HDIM + lane],     a0);
            a1 = fmaf(__shfl(h2, k + 1, 64), w_e1[(HDIM + k + 1) * HDIM + lane], a1);
        }
        bbv = a0 + a1;
    }

    const float e1 = fmaxf(bbv + b_e1[lane], 0.f);
    float a0 = b_e2[lane], a1 = 0.f;
    #pragma unroll 8
    for (int k = 0; k < HDIM; k += 2) {
        a0 = fmaf(__shfl(e1, k, 64),     w_e2[k * HDIM + lane],       a0);
        a1 = fmaf(__shfl(e1, k + 1, 64), w_e2[(k + 1) * HDIM + lane], a1);
    }
    E2[(size_t)wave * HDIM + lane] = fmaxf(a0 + a1, 0.f);
}

// K2 v3: 256 blocks x 1024 threads (16 waves) = exactly 1 block/CU.
// Each block computes 2 consecutive hidden rows (halves E2 traffic, 2x ILP).
// agg: wave wid covers j in [32*wid, 32*wid+32) for BOTH rows.
// tail: waves split into two 8-wave groups (one per row); each layer's K=64
// dot is split 8 ways across the group's waves with LDS partial-reduce.
__global__ __launch_bounds__(1024) void k_agg_out(
    const float* __restrict__ adj,   // (B,N,N)
    const float* __restrict__ E2,    // (B,N,64)
    const float* __restrict__ w_n1, const float* __restrict__ b_n1,
    const float* __restrict__ w_n2, const float* __restrict__ b_n2,
    const float* __restrict__ w_out, // (64,128)
    const float* __restrict__ b_out, // (128)
    float* __restrict__ out)         // (B,H,128)
{
    const int blk  = blockIdx.x;          // 0..255
    const int b    = blk >> 6;            // /64
    const int pair = blk & 63;            // 2 rows per block
    const int wid  = threadIdx.x >> 6;    // 0..15
    const int lane = threadIdx.x & 63;

    const int i0 = VV + pair * 2;         // receiver rows i0, i0+1
    const float* adjr0 = adj + ((size_t)b * NN + i0) * NN;
    const float* adjr1 = adjr0 + NN;
    const int j0 = wid * 32;

    // adj weights for this wave's 32 senders, both rows (one coalesced load)
    const float adjv = (lane < 32) ? adjr0[j0 + lane] : adjr1[j0 + lane - 32];
    const float* e2b = E2 + ((size_t)b * NN + j0) * HDIM;

    float p0 = 0.f, p1 = 0.f, q0 = 0.f, q1 = 0.f;
    #pragma unroll
    for (int jj = 0; jj < 32; jj += 2) {
        const float e0 = e2b[jj * HDIM + lane];
        const float e1 = e2b[(jj + 1) * HDIM + lane];
        p0 = fmaf(__shfl(adjv, jj, 64),      e0, p0);
        q0 = fmaf(__shfl(adjv, 32 + jj, 64), e0, q0);
        p1 = fmaf(__shfl(adjv, jj + 1, 64),  e1, p1);
        q1 = fmaf(__shfl(adjv, 33 + jj, 64), e1, q1);
    }

    __shared__ float redA[16][2][HDIM];   // 8 KB
    redA[wid][0][lane] = p0 + p1;
    redA[wid][1][lane] = q0 + q1;
    __syncthreads();

    const int g  = wid >> 3;   // row this wave's group handles (0/1)
    const int w8 = wid & 7;    // wave index within group

    // agg for row g (redundant per wave of the group — cheap LDS reads)
    float agg = 0.f;
    #pragma unroll
    for (int w = 0; w < 16; ++w) agg += redA[w][g][lane];

    // layer n1: K split 8 ways across the group's waves
    __shared__ float redB[16][HDIM];      // 4 KB
    {
        float t0 = 0.f, t1 = 0.f;
        #pragma unroll
        for (int t = 0; t < 8; t += 2) {
            const int k = 8 * w8 + t;
            t0 = fmaf(__shfl(agg, k, 64),     w_n1[k * HDIM + lane],       t0);
            t1 = fmaf(__shfl(agg, k + 1, 64), w_n1[(k + 1) * HDIM + lane], t1);
        }
        redB[wid][lane] = t0 + t1;
    }
    __syncthreads();
    float n1 = b_n1[lane];
    #pragma unroll
    for (int w = 0; w < 8; ++w) n1 += redB[g * 8 + w][lane];
    n1 = fmaxf(n1, 0.f);

    // layer n2
    __shared__ float redC[16][HDIM];      // 4 KB
    {
        float t0 = 0.f, t1 = 0.f;
        #pragma unroll
        for (int t = 0; t < 8; t += 2) {
            const int k = 8 * w8 + t;
            t0 = fmaf(__shfl(n1, k, 64),     w_n2[k * HDIM + lane],       t0);
            t1 = fmaf(__shfl(n1, k + 1, 64), w_n2[(k + 1) * HDIM + lane], t1);
        }
        redC[wid][lane] = t0 + t1;
    }
    __syncthreads();
    float n2 = b_n2[lane];
    #pragma unroll
    for (int w = 0; w < 8; ++w) n2 += redC[g * 8 + w][lane];
    n2 = fmaxf(n2, 0.f);

    // out layer: 128 outputs, K split 8 ways
    __shared__ float redD[16][TD];        // 8 KB
    {
        float o0 = 0.f, o1 = 0.f;
        #pragma unroll
        for (int t = 0; t < 8; ++t) {
            const int k = 8 * w8 + t;
            const float v = __shfl(n2, k, 64);
            o0 = fmaf(v, w_out[k * TD + lane],      o0);
            o1 = fmaf(v, w_out[k * TD + 64 + lane], o1);
        }
        redD[wid][lane]      = o0;
        redD[wid][64 + lane] = o1;
    }
    __syncthreads();

    // final write: waves 0,1 of each group cover cols [0,64) and [64,128)
    if (w8 < 2) {
        const int col = w8 * 64 + lane;
        float o = b_out[col];
        #pragma unroll
        for (int w = 0; w < 8; ++w) o += redD[g * 8 + w][col];
        const int orow = b * HH + pair * 2 + g;
        out[(size_t)orow * TD + col] = o;
    }
}

extern "C" void kernel_launch(void* const* d_in, const int* in_sizes, int n_in,
                              void* d_out, int out_size, void* d_ws, size_t ws_size,
                              hipStream_t stream) {
    const float* x     = (const float*)d_in[0];
    const float* adj   = (const float*)d_in[1];
    const float* w_in1 = (const float*)d_in[2];
    const float* b_in1 = (const float*)d_in[3];
    const float* w_in2 = (const float*)d_in[4];
    const float* b_in2 = (const float*)d_in[5];
    const float* w_e1  = (const float*)d_in[6];
    const float* b_e1  = (const float*)d_in[7];
    const float* w_e2  = (const float*)d_in[8];
    const float* b_e2  = (const float*)d_in[9];
    const float* w_n1  = (const float*)d_in[10];
    const float* b_n1  = (const float*)d_in[11];
    const float* w_n2  = (const float*)d_in[12];
    const float* b_n2  = (const float*)d_in[13];
    const float* w_out = (const float*)d_in[14];
    const float* b_out = (const float*)d_in[15];
    float* out = (float*)d_out;
    float* E2  = (float*)d_ws;   // B*N*64 floats = 512 KiB

    // K1: B*N = 2048 waves -> 512 blocks of 256 threads
    k_rowpipe<<<(BQ * NN * 64) / 256, 256, 0, stream>>>(
        x, w_in1, b_in1, w_in2, b_in2, w_e1, b_e1, w_e2, b_e2, E2);
    // K2: 256 blocks x 1024 threads, 2 hidden rows per block
    k_agg_out<<<BQ * HH / 2, 1024, 0, stream>>>(
        adj, E2, w_n1, b_n1, w_n2, b_n2, w_out, b_out, out);
}

// Round 8
// 20.425 us; speedup vs baseline: 3.6590x; 1.0774x over previous
//
#include <hip/hip_runtime.h>

// Shapes (compile-time constants from the reference)
#define BQ 4     // B
#define VV 384   // V visible nodes
#define HH 128   // H hidden nodes
#define NN 512   // N = V + H
#define HDIM 64  // HD
#define TD 128   // T*D

// K1: visible rows only (hidden rows' E2 is a constant vector handled in K2).
// 2 waves per row: wave half hf covers K-half of every layer; LDS partial
// reduce between layers. Block = 256 thr = 2 rows x 2 halves. Grid = 768.
__global__ __launch_bounds__(256) void k_rowpipe(
    const float* __restrict__ x,       // (B,V,128) ; flat row = b*V+j
    const float* __restrict__ w_in1,   // (128,64)
    const float* __restrict__ b_in1,   // (64)
    const float* __restrict__ w_in2,   // (64,64)
    const float* __restrict__ b_in2,   // (64)
    const float* __restrict__ w_e1,    // (128,64) ; rows [64:128) = sender half
    const float* __restrict__ b_e1,    // (64)
    const float* __restrict__ w_e2,    // (64,64)
    const float* __restrict__ b_e2,    // (64)
    float* __restrict__ E2)            // (B*V,64) in workspace
{
    __shared__ float part[4][2][2][HDIM];   // [layer][row_local][half][lane]

    const int wid  = threadIdx.x >> 6;    // 0..3
    const int lane = threadIdx.x & 63;
    const int rl   = wid >> 1;            // row within block
    const int hf   = wid & 1;             // K-half
    const int row  = blockIdx.x * 2 + rl; // 0..1535 == b*V+j

    const float* xr = x + (size_t)row * TD;
    const float xv = xr[64 * hf + lane];  // my half of the x row

    // layer in1: K=128, my half is kg in [64*hf, 64*hf+64)
    float a0 = 0.f, a1 = 0.f;
    #pragma unroll 8
    for (int k = 0; k < 64; k += 2) {
        const int kg = 64 * hf + k;
        a0 = fmaf(__shfl(xv, k, 64),     w_in1[kg * HDIM + lane],       a0);
        a1 = fmaf(__shfl(xv, k + 1, 64), w_in1[(kg + 1) * HDIM + lane], a1);
    }
    part[0][rl][hf][lane] = a0 + a1;
    __syncthreads();
    const float h1 = fmaxf(part[0][rl][0][lane] + part[0][rl][1][lane] + b_in1[lane], 0.f);

    // layer in2: K=64, my half kg in [32*hf, 32*hf+32)
    a0 = 0.f; a1 = 0.f;
    #pragma unroll 8
    for (int k = 0; k < 32; k += 2) {
        const int kg = 32 * hf + k;
        a0 = fmaf(__shfl(h1, kg, 64),     w_in2[kg * HDIM + lane],       a0);
        a1 = fmaf(__shfl(h1, kg + 1, 64), w_in2[(kg + 1) * HDIM + lane], a1);
    }
    part[1][rl][hf][lane] = a0 + a1;
    __syncthreads();
    const float h2 = fmaxf(part[1][rl][0][lane] + part[1][rl][1][lane] + b_in2[lane], 0.f);

    // sender-side edge contribution: bb = h2 @ w_e1[HD:]
    a0 = 0.f; a1 = 0.f;
    #pragma unroll 8
    for (int k = 0; k < 32; k += 2) {
        const int kg = 32 * hf + k;
        a0 = fmaf(__shfl(h2, kg, 64),     w_e1[(HDIM + kg) * HDIM + lane],     a0);
        a1 = fmaf(__shfl(h2, kg + 1, 64), w_e1[(HDIM + kg + 1) * HDIM + lane], a1);
    }
    part[2][rl][hf][lane] = a0 + a1;
    __syncthreads();
    const float e1 = fmaxf(part[2][rl][0][lane] + part[2][rl][1][lane] + b_e1[lane], 0.f);

    // edge layer 2
    a0 = 0.f; a1 = 0.f;
    #pragma unroll 8
    for (int k = 0; k < 32; k += 2) {
        const int kg = 32 * hf + k;
        a0 = fmaf(__shfl(e1, kg, 64),     w_e2[kg * HDIM + lane],       a0);
        a1 = fmaf(__shfl(e1, kg + 1, 64), w_e2[(kg + 1) * HDIM + lane], a1);
    }
    part[3][rl][hf][lane] = a0 + a1;
    __syncthreads();
    if (hf == 0)
        E2[(size_t)row * HDIM + lane] =
            fmaxf(part[3][rl][0][lane] + part[3][rl][1][lane] + b_e2[lane], 0.f);
}

// K2: 256 blocks x 1024 threads (16 waves), 2 hidden rows per block.
// Waves 0-11: visible-sender agg (j in [0,384)). Waves 12-15: hidden-sender
// adj row-sums (tree reduce); wave 12 also computes the constant e2c vector.
// Tail: two 8-wave groups (one per row), K split 8 ways, LDS reduce.
__global__ __launch_bounds__(1024) void k_agg_out(
    const float* __restrict__ adj,   // (B,N,N)
    const float* __restrict__ E2,    // (B*V,64)
    const float* __restrict__ b_e1, const float* __restrict__ w_e2,
    const float* __restrict__ b_e2,
    const float* __restrict__ w_n1, const float* __restrict__ b_n1,
    const float* __restrict__ w_n2, const float* __restrict__ b_n2,
    const float* __restrict__ w_out, // (64,128)
    const float* __restrict__ b_out, // (128)
    float* __restrict__ out)         // (B,H,128)
{
    const int blk  = blockIdx.x;          // 0..255
    const int b    = blk >> 6;
    const int pair = blk & 63;
    const int wid  = threadIdx.x >> 6;    // 0..15
    const int lane = threadIdx.x & 63;

    const int i0 = VV + pair * 2;
    const float* adjr0 = adj + ((size_t)b * NN + i0) * NN;
    const float* adjr1 = adjr0 + NN;
    const int j0 = wid * 32;              // waves 0-11 visible, 12-15 hidden

    // 32 senders for both rows in one coalesced load
    const float adjv = (lane < 32) ? adjr0[j0 + lane] : adjr1[j0 + lane - 32];

    __shared__ float redA[12][2][HDIM];
    __shared__ float hs[4][2];
    __shared__ float e2c[HDIM];

    if (wid < 12) {
        const float* e2b = E2 + ((size_t)b * VV + j0) * HDIM;
        float p0 = 0.f, p1 = 0.f, q0 = 0.f, q1 = 0.f;
        #pragma unroll 8
        for (int jj = 0; jj < 32; jj += 2) {
            const float e0 = e2b[jj * HDIM + lane];
            const float e1 = e2b[(jj + 1) * HDIM + lane];
            p0 = fmaf(__shfl(adjv, jj, 64),      e0, p0);
            q0 = fmaf(__shfl(adjv, 32 + jj, 64), e0, q0);
            p1 = fmaf(__shfl(adjv, jj + 1, 64),  e1, p1);
            q1 = fmaf(__shfl(adjv, 33 + jj, 64), e1, q1);
        }
        redA[wid][0][lane] = p0 + p1;
        redA[wid][1][lane] = q0 + q1;
    } else {
        // hidden senders: row-sum of adj chunk per row via 32-lane tree
        float s = adjv;
        s += __shfl_xor(s, 1, 64);
        s += __shfl_xor(s, 2, 64);
        s += __shfl_xor(s, 4, 64);
        s += __shfl_xor(s, 8, 64);
        s += __shfl_xor(s, 16, 64);
        if (lane == 0)  hs[wid - 12][0] = s;
        if (lane == 32) hs[wid - 12][1] = s;
        if (wid == 12) {
            // constant hidden-sender E2 vector: relu(relu(b_e1)@w_e2 + b_e2)
            const float e1c = fmaxf(b_e1[lane], 0.f);
            float t0 = b_e2[lane], t1 = 0.f;
            #pragma unroll 8
            for (int k = 0; k < HDIM; k += 2) {
                t0 = fmaf(__shfl(e1c, k, 64),     w_e2[k * HDIM + lane],       t0);
                t1 = fmaf(__shfl(e1c, k + 1, 64), w_e2[(k + 1) * HDIM + lane], t1);
            }
            e2c[lane] = fmaxf(t0 + t1, 0.f);
        }
    }
    __syncthreads();

    const int g  = wid >> 3;   // row this wave's group handles (0/1)
    const int w8 = wid & 7;

    const float hsum = hs[0][g] + hs[1][g] + hs[2][g] + hs[3][g];
    float agg = hsum * e2c[lane];
    #pragma unroll
    for (int w = 0; w < 12; ++w) agg += redA[w][g][lane];

    // layer n1: K split 8 ways across the group's waves
    __shared__ float redB[16][HDIM];
    {
        float t0 = 0.f, t1 = 0.f;
        #pragma unroll
        for (int t = 0; t < 8; t += 2) {
            const int k = 8 * w8 + t;
            t0 = fmaf(__shfl(agg, k, 64),     w_n1[k * HDIM + lane],       t0);
            t1 = fmaf(__shfl(agg, k + 1, 64), w_n1[(k + 1) * HDIM + lane], t1);
        }
        redB[wid][lane] = t0 + t1;
    }
    __syncthreads();
    float n1 = b_n1[lane];
    #pragma unroll
    for (int w = 0; w < 8; ++w) n1 += redB[g * 8 + w][lane];
    n1 = fmaxf(n1, 0.f);

    // layer n2
    __shared__ float redC[16][HDIM];
    {
        float t0 = 0.f, t1 = 0.f;
        #pragma unroll
        for (int t = 0; t < 8; t += 2) {
            const int k = 8 * w8 + t;
            t0 = fmaf(__shfl(n1, k, 64),     w_n2[k * HDIM + lane],       t0);
            t1 = fmaf(__shfl(n1, k + 1, 64), w_n2[(k + 1) * HDIM + lane], t1);
        }
        redC[wid][lane] = t0 + t1;
    }
    __syncthreads();
    float n2 = b_n2[lane];
    #pragma unroll
    for (int w = 0; w < 8; ++w) n2 += redC[g * 8 + w][lane];
    n2 = fmaxf(n2, 0.f);

    // out layer: 128 outputs, K split 8 ways
    __shared__ float redD[16][TD];
    {
        float o0 = 0.f, o1 = 0.f;
        #pragma unroll
        for (int t = 0; t < 8; ++t) {
            const int k = 8 * w8 + t;
            const float v = __shfl(n2, k, 64);
            o0 = fmaf(v, w_out[k * TD + lane],      o0);
            o1 = fmaf(v, w_out[k * TD + 64 + lane], o1);
        }
        redD[wid][lane]      = o0;
        redD[wid][64 + lane] = o1;
    }
    __syncthreads();

    if (w8 < 2) {
        const int col = w8 * 64 + lane;
        float o = b_out[col];
        #pragma unroll
        for (int w = 0; w < 8; ++w) o += redD[g * 8 + w][col];
        const int orow = b * HH + pair * 2 + g;
        out[(size_t)orow * TD + col] = o;
    }
}

extern "C" void kernel_launch(void* const* d_in, const int* in_sizes, int n_in,
                              void* d_out, int out_size, void* d_ws, size_t ws_size,
                              hipStream_t stream) {
    const float* x     = (const float*)d_in[0];
    const float* adj   = (const float*)d_in[1];
    const float* w_in1 = (const float*)d_in[2];
    const float* b_in1 = (const float*)d_in[3];
    const float* w_in2 = (const float*)d_in[4];
    const float* b_in2 = (const float*)d_in[5];
    const float* w_e1  = (const float*)d_in[6];
    const float* b_e1  = (const float*)d_in[7];
    const float* w_e2  = (const float*)d_in[8];
    const float* b_e2  = (const float*)d_in[9];
    const float* w_n1  = (const float*)d_in[10];
    const float* b_n1  = (const float*)d_in[11];
    const float* w_n2  = (const float*)d_in[12];
    const float* b_n2  = (const float*)d_in[13];
    const float* w_out = (const float*)d_in[14];
    const float* b_out = (const float*)d_in[15];
    float* out = (float*)d_out;
    float* E2  = (float*)d_ws;   // B*V*64 floats = 384 KiB

    // K1: 1536 visible rows, 2 waves/row -> 768 blocks of 256 threads
    k_rowpipe<<<(BQ * VV) / 2, 256, 0, stream>>>(
        x, w_in1, b_in1, w_in2, b_in2, w_e1, b_e1, w_e2, b_e2, E2);
    // K2: 256 blocks x 1024 threads, 2 hidden rows per block
    k_agg_out<<<BQ * HH / 2, 1024, 0, stream>>>(
        adj, E2, b_e1, w_e2, b_e2, w_n1, b_n1, w_n2, b_n2, w_out, b_out, out);
}

// Round 9
// 18.284 us; speedup vs baseline: 4.0874x; 1.1171x over previous
//
#include <hip/hip_runtime.h>

// Shapes (compile-time constants from the reference)
#define BQ 4     // B
#define VV 384   // V visible nodes
#define HH 128   // H hidden nodes
#define NN 512   // N = V + H
#define HDIM 64  // HD
#define TD 128   // T*D

// Wave-uniform broadcast: readlane (VALU/SGPR, ~4cyc) instead of __shfl
// (ds_bpermute, ~60+cyc LDS-crossbar latency). Index must be wave-uniform.
__device__ __forceinline__ float BCAST(float v, int l) {
    return __int_as_float(__builtin_amdgcn_readlane(__float_as_int(v), l));
}

// K1: visible rows only (hidden rows' E2 is a constant vector handled in K2).
// 2 waves per row: wave half hf covers K-half of every layer; LDS partial
// reduce between layers. Block = 256 thr = 2 rows x 2 halves. Grid = 768.
__global__ __launch_bounds__(256) void k_rowpipe(
    const float* __restrict__ x,       // (B,V,128) ; flat row = b*V+j
    const float* __restrict__ w_in1,   // (128,64)
    const float* __restrict__ b_in1,   // (64)
    const float* __restrict__ w_in2,   // (64,64)
    const float* __restrict__ b_in2,   // (64)
    const float* __restrict__ w_e1,    // (128,64) ; rows [64:128) = sender half
    const float* __restrict__ b_e1,    // (64)
    const float* __restrict__ w_e2,    // (64,64)
    const float* __restrict__ b_e2,    // (64)
    float* __restrict__ E2)            // (B*V,64) in workspace
{
    __shared__ float part[4][2][2][HDIM];   // [layer][row_local][half][lane]

    const int wid  = threadIdx.x >> 6;    // 0..3
    const int lane = threadIdx.x & 63;
    const int rl   = wid >> 1;            // row within block
    const int hf   = wid & 1;             // K-half
    const int row  = blockIdx.x * 2 + rl; // 0..1535 == b*V+j

    const float* xr = x + (size_t)row * TD;
    const float xv = xr[64 * hf + lane];  // my half of the x row

    // layer in1: K=128, my half is kg in [64*hf, 64*hf+64)
    float a0 = 0.f, a1 = 0.f;
    #pragma unroll 8
    for (int k = 0; k < 64; k += 2) {
        const int kg = 64 * hf + k;
        a0 = fmaf(BCAST(xv, k),     w_in1[kg * HDIM + lane],       a0);
        a1 = fmaf(BCAST(xv, k + 1), w_in1[(kg + 1) * HDIM + lane], a1);
    }
    part[0][rl][hf][lane] = a0 + a1;
    __syncthreads();
    const float h1 = fmaxf(part[0][rl][0][lane] + part[0][rl][1][lane] + b_in1[lane], 0.f);

    // layer in2: K=64, my half kg in [32*hf, 32*hf+32)
    a0 = 0.f; a1 = 0.f;
    #pragma unroll 8
    for (int k = 0; k < 32; k += 2) {
        const int kg = 32 * hf + k;
        a0 = fmaf(BCAST(h1, kg),     w_in2[kg * HDIM + lane],       a0);
        a1 = fmaf(BCAST(h1, kg + 1), w_in2[(kg + 1) * HDIM + lane], a1);
    }
    part[1][rl][hf][lane] = a0 + a1;
    __syncthreads();
    const float h2 = fmaxf(part[1][rl][0][lane] + part[1][rl][1][lane] + b_in2[lane], 0.f);

    // sender-side edge contribution: bb = h2 @ w_e1[HD:]
    a0 = 0.f; a1 = 0.f;
    #pragma unroll 8
    for (int k = 0; k < 32; k += 2) {
        const int kg = 32 * hf + k;
        a0 = fmaf(BCAST(h2, kg),     w_e1[(HDIM + kg) * HDIM + lane],     a0);
        a1 = fmaf(BCAST(h2, kg + 1), w_e1[(HDIM + kg + 1) * HDIM + lane], a1);
    }
    part[2][rl][hf][lane] = a0 + a1;
    __syncthreads();
    const float e1 = fmaxf(part[2][rl][0][lane] + part[2][rl][1][lane] + b_e1[lane], 0.f);

    // edge layer 2
    a0 = 0.f; a1 = 0.f;
    #pragma unroll 8
    for (int k = 0; k < 32; k += 2) {
        const int kg = 32 * hf + k;
        a0 = fmaf(BCAST(e1, kg),     w_e2[kg * HDIM + lane],       a0);
        a1 = fmaf(BCAST(e1, kg + 1), w_e2[(kg + 1) * HDIM + lane], a1);
    }
    part[3][rl][hf][lane] = a0 + a1;
    __syncthreads();
    if (hf == 0)
        E2[(size_t)row * HDIM + lane] =
            fmaxf(part[3][rl][0][lane] + part[3][rl][1][lane] + b_e2[lane], 0.f);
}

// K2: 256 blocks x 1024 threads (16 waves), 2 hidden rows per block.
// Waves 0-11: visible-sender agg (j in [0,384)). Waves 12-15: hidden-sender
// adj row-sums (tree reduce); wave 12 also computes the constant e2c vector.
// Tail: two 8-wave groups (one per row), K split 8 ways, LDS reduce.
__global__ __launch_bounds__(1024) void k_agg_out(
    const float* __restrict__ adj,   // (B,N,N)
    const float* __restrict__ E2,    // (B*V,64)
    const float* __restrict__ b_e1, const float* __restrict__ w_e2,
    const float* __restrict__ b_e2,
    const float* __restrict__ w_n1, const float* __restrict__ b_n1,
    const float* __restrict__ w_n2, const float* __restrict__ b_n2,
    const float* __restrict__ w_out, // (64,128)
    const float* __restrict__ b_out, // (128)
    float* __restrict__ out)         // (B,H,128)
{
    const int blk  = blockIdx.x;          // 0..255
    const int b    = blk >> 6;
    const int pair = blk & 63;
    const int wid  = threadIdx.x >> 6;    // 0..15
    const int lane = threadIdx.x & 63;

    const int i0 = VV + pair * 2;
    const float* adjr0 = adj + ((size_t)b * NN + i0) * NN;
    const float* adjr1 = adjr0 + NN;
    const int j0 = wid * 32;              // waves 0-11 visible, 12-15 hidden

    // 32 senders for both rows in one coalesced load
    const float adjv = (lane < 32) ? adjr0[j0 + lane] : adjr1[j0 + lane - 32];

    __shared__ float redA[12][2][HDIM];
    __shared__ float hs[4][2];
    __shared__ float e2c[HDIM];

    if (wid < 12) {
        const float* e2b = E2 + ((size_t)b * VV + j0) * HDIM;
        float p0 = 0.f, p1 = 0.f, q0 = 0.f, q1 = 0.f;
        #pragma unroll 8
        for (int jj = 0; jj < 32; jj += 2) {
            const float e0 = e2b[jj * HDIM + lane];
            const float e1 = e2b[(jj + 1) * HDIM + lane];
            p0 = fmaf(BCAST(adjv, jj),      e0, p0);
            q0 = fmaf(BCAST(adjv, 32 + jj), e0, q0);
            p1 = fmaf(BCAST(adjv, jj + 1),  e1, p1);
            q1 = fmaf(BCAST(adjv, 33 + jj), e1, q1);
        }
        redA[wid][0][lane] = p0 + p1;
        redA[wid][1][lane] = q0 + q1;
    } else {
        // hidden senders: row-sum of adj chunk per row via 32-lane tree
        float s = adjv;
        s += __shfl_xor(s, 1, 64);
        s += __shfl_xor(s, 2, 64);
        s += __shfl_xor(s, 4, 64);
        s += __shfl_xor(s, 8, 64);
        s += __shfl_xor(s, 16, 64);
        if (lane == 0)  hs[wid - 12][0] = s;
        if (lane == 32) hs[wid - 12][1] = s;
        if (wid == 12) {
            // constant hidden-sender E2 vector: relu(relu(b_e1)@w_e2 + b_e2)
            const float e1c = fmaxf(b_e1[lane], 0.f);
            float t0 = b_e2[lane], t1 = 0.f;
            #pragma unroll 8
            for (int k = 0; k < HDIM; k += 2) {
                t0 = fmaf(BCAST(e1c, k),     w_e2[k * HDIM + lane],       t0);
                t1 = fmaf(BCAST(e1c, k + 1), w_e2[(k + 1) * HDIM + lane], t1);
            }
            e2c[lane] = fmaxf(t0 + t1, 0.f);
        }
    }
    __syncthreads();

    const int g  = wid >> 3;   // row this wave's group handles (0/1)
    const int w8 = wid & 7;

    const float hsum = hs[0][g] + hs[1][g] + hs[2][g] + hs[3][g];
    float agg = hsum * e2c[lane];
    #pragma unroll
    for (int w = 0; w < 12; ++w) agg += redA[w][g][lane];

    // layer n1: K split 8 ways across the group's waves
    __shared__ float redB[16][HDIM];
    {
        float t0 = 0.f, t1 = 0.f;
        #pragma unroll
        for (int t = 0; t < 8; t += 2) {
            const int k = 8 * w8 + t;
            t0 = fmaf(BCAST(agg, k),     w_n1[k * HDIM + lane],       t0);
            t1 = fmaf(BCAST(agg, k + 1), w_n1[(k + 1) * HDIM + lane], t1);
        }
        redB[wid][lane] = t0 + t1;
    }
    __syncthreads();
    float n1 = b_n1[lane];
    #pragma unroll
    for (int w = 0; w < 8; ++w) n1 += redB[g * 8 + w][lane];
    n1 = fmaxf(n1, 0.f);

    // layer n2
    __shared__ float redC[16][HDIM];
    {
        float t0 = 0.f, t1 = 0.f;
        #pragma unroll
        for (int t = 0; t < 8; t += 2) {
            const int k = 8 * w8 + t;
            t0 = fmaf(BCAST(n1, k),     w_n2[k * HDIM + lane],       t0);
            t1 = fmaf(BCAST(n1, k + 1), w_n2[(k + 1) * HDIM + lane], t1);
        }
        redC[wid][lane] = t0 + t1;
    }
    __syncthreads();
    float n2 = b_n2[lane];
    #pragma unroll
    for (int w = 0; w < 8; ++w) n2 += redC[g * 8 + w][lane];
    n2 = fmaxf(n2, 0.f);

    // out layer: 128 outputs, K split 8 ways
    __shared__ float redD[16][TD];
    {
        float o0 = 0.f, o1 = 0.f;
        #pragma unroll
        for (int t = 0; t < 8; ++t) {
            const int k = 8 * w8 + t;
            const float v = BCAST(n2, k);
            o0 = fmaf(v, w_out[k * TD + lane],      o0);
            o1 = fmaf(v, w_out[k * TD + 64 + lane], o1);
        }
        redD[wid][lane]      = o0;
        redD[wid][64 + lane] = o1;
    }
    __syncthreads();

    if (w8 < 2) {
        const int col = w8 * 64 + lane;
        float o = b_out[col];
        #pragma unroll
        for (int w = 0; w < 8; ++w) o += redD[g * 8 + w][col];
        const int orow = b * HH + pair * 2 + g;
        out[(size_t)orow * TD + col] = o;
    }
}

extern "C" void kernel_launch(void* const* d_in, const int* in_sizes, int n_in,
                              void* d_out, int out_size, void* d_ws, size_t ws_size,
                              hipStream_t stream) {
    const float* x     = (const float*)d_in[0];
    const float* adj   = (const float*)d_in[1];
    const float* w_in1 = (const float*)d_in[2];
    const float* b_in1 = (const float*)d_in[3];
    const float* w_in2 = (const float*)d_in[4];
    const float* b_in2 = (const float*)d_in[5];
    const float* w_e1  = (const float*)d_in[6];
    const float* b_e1  = (const float*)d_in[7];
    const float* w_e2  = (const float*)d_in[8];
    const float* b_e2  = (const float*)d_in[9];
    const float* w_n1  = (const float*)d_in[10];
    const float* b_n1  = (const float*)d_in[11];
    const float* w_n2  = (const float*)d_in[12];
    const float* b_n2  = (const float*)d_in[13];
    const float* w_out = (const float*)d_in[14];
    const float* b_out = (const float*)d_in[15];
    float* out = (float*)d_out;
    float* E2  = (float*)d_ws;   // B*V*64 floats = 384 KiB

    // K1: 1536 visible rows, 2 waves/row -> 768 blocks of 256 threads
    k_rowpipe<<<(BQ * VV) / 2, 256, 0, stream>>>(
        x, w_in1, b_in1, w_in2, b_in2, w_e1, b_e1, w_e2, b_e2, E2);
    // K2: 256 blocks x 1024 threads, 2 hidden rows per block
    k_agg_out<<<BQ * HH / 2, 1024, 0, stream>>>(
        adj, E2, b_e1, w_e2, b_e2, w_n1, b_n1, w_n2, b_n2, w_out, b_out, out);
}